// Round 15
// baseline (695.632 us; speedup 1.0000x reference)
//
#include <hip/hip_runtime.h>
#include <hip/hip_bf16.h>
#include <math.h>

#define B_ 4
#define N_ 32768
#define S_ 8192
#define K_ 16
#define CIN 64
#define COUT 128
#define MID_ 32
#define EPS_ 1e-5f
#define NTILE 2048   // (B_*S_)/16 epilogue tiles

typedef __attribute__((ext_vector_type(8))) short s16x8;
typedef __attribute__((ext_vector_type(4))) float f32x4;

// static scratch (written fully every call before being read)
__device__ ushort g_attn[(size_t)B_ * S_ * COUT];   // attn output, bf16, row-major
__device__ ushort g_sfeat[(size_t)B_ * S_ * CIN];   // gathered s_feat, bf16
__device__ float  g_part[NTILE * 8 * 2];            // GN partial sums per tile/group
__device__ float  g_stats[64];                      // GN mean/rstd per (b,g)
// fused weights: [0,2048) Wqa1 32x64; [2048,4096) Wka1 32x64; [4096,8192) Wpa1 32x128
__device__ float  g_fw[8192];

// hardware bf16 converts (v_cvt_pk_bf16_f32)
__device__ __forceinline__ uint pk2(float lo, float hi) {
  __hip_bfloat162 h = __float22bfloat162_rn(make_float2(lo, hi));
  return *(uint*)&h;
}
__device__ __forceinline__ ushort f2bf(float f) {
  __hip_bfloat16 h = __float2bfloat16(f);
  return *(ushort*)&h;
}
__device__ __forceinline__ int4 pack8(float4 a, float4 b) {
  int4 o;
  o.x = pk2(a.x, a.y); o.y = pk2(a.z, a.w);
  o.z = pk2(b.x, b.y); o.w = pk2(b.z, b.w);
  return o;
}
__device__ __forceinline__ f32x4 mfma16(s16x8 a, s16x8 b, f32x4 c) {
  return __builtin_amdgcn_mfma_f32_16x16x32_bf16(a, b, c, 0, 0, 0);
}
__device__ __forceinline__ int sw7(int row) { return (row & 7) ^ ((row & 8) >> 2); }
__device__ __forceinline__ int sw2(int row) { return (row & 3) ^ ((row >> 2) & 3); }

// weight B-frag reads, swizzled rows of 256B / 128B
__device__ __forceinline__ s16x8 ldw256(const ushort* W, int row, int g) {
  return *(const s16x8*)((const char*)W + row * 256 + ((g ^ (row & 7)) << 4));
}
__device__ __forceinline__ s16x8 ldw128(const ushort* W, int row, int g) {
  return *(const s16x8*)((const char*)W + row * 128 + ((g ^ (row & 7)) << 4));
}
__device__ __forceinline__ s16x8 ldfrag_g8(const float* p) {
  float4 a = *(const float4*)p, b = *(const float4*)(p + 4);
  union { int4 i; s16x8 s; } u;
  u.i = pack8(a, b);
  return u.s;
}
// full t1 store: 16x128 bf16, 256B rows, slot ^= row&15 (perfect 16-slot spread)
__device__ __forceinline__ void st16f(char* bufb, int t, f32x4 c, int l, int cq,
                                      bool dorelu) {
  const int colp = (l & 15) + 16 * t;
  const int g = colp >> 3;
  const int off = (colp & 7) * 2;
  #pragma unroll
  for (int rr = 0; rr < 4; ++rr) {
    const int row = cq * 4 + rr;
    float v = dorelu ? fmaxf(c[rr], 0.f) : c[rr];
    *(ushort*)(bufb + row * 256 + ((g ^ (row & 15)) << 4) + off) = f2bf(v);
  }
}
// store 16x32 a1 tile (row stride 64B, sw2) with relu, b16 writes
__device__ __forceinline__ void st16_a1(char* bufb, int t, f32x4 c, int l, int cq) {
  const int colp = (l & 15) + 16 * t;   // 0..31
  const int g = colp >> 3;              // 0..3
  const int off = (colp & 7) * 2;
  #pragma unroll
  for (int rr = 0; rr < 4; ++rr) {
    const int row = cq * 4 + rr;
    *(ushort*)(bufb + row * 64 + ((g ^ sw2(row)) << 4) + off) =
        f2bf(fmaxf(c[rr], 0.f));
  }
}
// k_post: 256B-row sbuf store with full row&15 spread
__device__ __forceinline__ void st16p(char* bufb, int t, f32x4 c, int l, int cq) {
  const int colp = (l & 15) + 16 * t;
  const int g = colp >> 3;
  const int off = (colp & 7) * 2;
  #pragma unroll
  for (int rr = 0; rr < 4; ++rr) {
    const int row = cq * 4 + rr;
    *(ushort*)(bufb + row * 256 + ((g ^ (row & 15)) << 4) + off) = f2bf(c[rr]);
  }
}

// ---------------- Kernel 0: fused weights  Wa1 @ {Wq, Wk, Wp2} ---------------
__global__ __launch_bounds__(256) void k_fuse(
    const float* __restrict__ Wq, const float* __restrict__ Wk,
    const float* __restrict__ Wp2, const float* __restrict__ Wa1)
{
  const int t = blockIdx.x * 256 + threadIdx.x;   // 0..8191
  if (t < 2048) {
    int m = t >> 6, c = t & 63;
    float s = 0.f;
    for (int o = 0; o < COUT; ++o) s += Wa1[m * COUT + o] * Wq[o * CIN + c];
    g_fw[t] = s;
  } else if (t < 4096) {
    int u = t - 2048;
    int m = u >> 6, c = u & 63;
    float s = 0.f;
    for (int o = 0; o < COUT; ++o) s += Wa1[m * COUT + o] * Wk[o * CIN + c];
    g_fw[t] = s;
  } else {
    int u = t - 4096;
    int m = u >> 7, c = u & 127;
    float s = 0.f;
    for (int o = 0; o < COUT; ++o) s += Wa1[m * COUT + o] * Wp2[o * COUT + c];
    g_fw[t] = s;
  }
}

// --- Kernel 1: attention core, cross-point software pipeline ----------------
// 640 thr = 10 waves, grid 256 (1 block/CU). arch cap = 65536/640 = 102.
// Per wave 9KB: double-buffered 4KB nfeat/t1 + 1KB a1.
// LDS: 62KB weights + 90KB sbuf = 155648 B.
// Pipeline: fT(i) read | vv/za on held fA(i) | issue gathers(i+1) |
//           fT MFMAs (cover HBM) | stage nfeat(i+1)+read fA(i+1) |
//           t1(i+1) MFMA+store (read next iter) | a1/softmax(i).
__global__ __launch_bounds__(640) void k_attn(
    const float* __restrict__ xyz, const float* __restrict__ feats,
    const int* __restrict__ idx_fps, const int* __restrict__ idx_knn,
    const float* __restrict__ Wv, const float* __restrict__ Wp1,
    const float* __restrict__ Wp2, const float* __restrict__ Wa2,
    float* __restrict__ out_xyz)
{
  __shared__ ushort lWv[COUT * CIN];     // 16 KB, 128B rows swz
  __shared__ ushort lWp1[COUT * 8];      // 2 KB, 16B rows linear
  __shared__ ushort lWp2[COUT * COUT];   // 32 KB, 256B rows swz
  __shared__ ushort lWka1[MID_ * CIN];   // 4 KB, 128B rows swz (holds -Wka1)
  __shared__ ushort lWpa1[MID_ * COUT];  // 8 KB, 256B rows swz
  __shared__ ushort sbuf[10 * 4608];     // per wave 9KB (2x4KB dbuf + 1KB a1)

  const int tid = threadIdx.x;
  const int w = tid >> 6, l = tid & 63;   // w = 0..9
  const int r = l & 15, cq = l >> 4;

  for (int i = tid; i < COUT * CIN / 2; i += 640) {
    int row = i >> 5; int kp = (i & 31) * 2;
    int g = kp >> 3;
    *(uint*)((char*)lWv + row * 128 + ((g ^ (row & 7)) << 4) + (kp & 7) * 2)
        = pk2(Wv[row * CIN + kp], Wv[row * CIN + kp + 1]);
  }
  if (tid < 512) { // Wp1 padded: 128 rows x 4 pairs
    int row = tid >> 2; int kp = (tid & 3) * 2;
    float lo = (kp < 3) ? Wp1[row * 3 + kp] : 0.f;
    float hi = (kp + 1 < 3) ? Wp1[row * 3 + kp + 1] : 0.f;
    *(uint*)((char*)lWp1 + row * 16 + kp * 2) = pk2(lo, hi);
  }
  for (int i = tid; i < COUT * CIN; i += 640) {
    int row = i >> 6; int kp = (i & 63) * 2;
    int g = kp >> 3;
    *(uint*)((char*)lWp2 + row * 256 + ((g ^ (row & 7)) << 4) + (kp & 7) * 2)
        = pk2(Wp2[row * COUT + kp], Wp2[row * COUT + kp + 1]);
  }
  for (int i = tid; i < MID_ * CIN / 2; i += 640) {   // -Wka1
    int row = i >> 5; int kp = (i & 31) * 2;
    int g = kp >> 3;
    const float* src = g_fw + 2048 + row * CIN + kp;
    *(uint*)((char*)lWka1 + row * 128 + ((g ^ (row & 7)) << 4) + (kp & 7) * 2)
        = pk2(-src[0], -src[1]);
  }
  for (int i = tid; i < MID_ * COUT / 2; i += 640) {  // Wpa1
    int row = i >> 6; int kp = (i & 63) * 2;
    int g = kp >> 3;
    const float* src = g_fw + 4096 + row * COUT + kp;
    *(uint*)((char*)lWpa1 + row * 256 + ((g ^ (row & 7)) << 4) + (kp & 7) * 2)
        = pk2(src[0], src[1]);
  }

  // register-resident Wa2 B-frags (8 n-tiles, 32 VGPR)
  s16x8 fWa2[8];
  #pragma unroll
  for (int t = 0; t < 8; ++t)
    fWa2[t] = ldfrag_g8(Wa2 + (16 * t + r) * MID_ + cq * 8);

  __syncthreads();

  char* base = (char*)sbuf + w * 9216;
  char* bufa = base + 8192;               // 1KB a1
  // waves 0-7: 13 points; waves 8-9: 12  (8*13 + 2*12 = 128/block)
  const int cnt  = (w < 8) ? 13 : 12;
  const int pid0 = blockIdx.x * 128 + ((w < 8) ? w * 13 : 104 + (w - 8) * 12);

  // ---- prologue: sfeat stage + qa1 GEMM (buf0 scratch) ----
  {
    const int rp = (r < cnt) ? r : 0;
    const int p = pid0 + rp;
    const int bb = p >> 13;
    const int si = idx_fps[p];
    const float* fs = feats + ((size_t)bb * N_ + si) * CIN;
    #pragma unroll
    for (int j = 0; j < 2; ++j) {
      int g = cq * 2 + j;
      int4 pks = pack8(*(const float4*)(fs + g * 8), *(const float4*)(fs + g * 8 + 4));
      *(int4*)(base + r * 128 + ((g ^ sw7(r)) << 4)) = pks;
      if (r < cnt) *(int4*)((char*)g_sfeat + (size_t)p * 128 + g * 16) = pks;
    }
    if (l < 3 * cnt) {
      int pi = l / 3, j = l - pi * 3;
      int pp = pid0 + pi;
      out_xyz[(size_t)pp * 3 + j] =
          xyz[((size_t)(pp >> 13) * N_ + idx_fps[pp]) * 3 + j];
    }
  }
  f32x4 qa1[2];
  qa1[0] = (f32x4){0, 0, 0, 0}; qa1[1] = (f32x4){0, 0, 0, 0};
  {
    s16x8 fS[2], fQ;
    #pragma unroll
    for (int ks = 0; ks < 2; ++ks)
      fS[ks] = *(const s16x8*)(base + r * 128 + (((ks * 4 + cq) ^ sw7(r)) << 4));
    #pragma unroll
    for (int ks = 0; ks < 2; ++ks)
      #pragma unroll
      for (int t = 0; t < 2; ++t) {
        fQ = ldfrag_g8(g_fw + (16 * t + r) * CIN + ks * 32 + cq * 8);
        qa1[t] = mfma16(fS[ks], fQ, qa1[t]);
      }
  }

  // ---- prologue: stage point 0 (nfeat + fA + t1) into buf0 ----
  s16x8 fAc[2];
  {
    const int bb = pid0 >> 13;
    const int nid = idx_knn[(size_t)pid0 * K_ + r];
    const float* fn = feats + ((size_t)bb * N_ + nid) * CIN + cq * 16;
    float4 f0 = ((const float4*)fn)[0], f1 = ((const float4*)fn)[1];
    float4 f2 = ((const float4*)fn)[2], f3 = ((const float4*)fn)[3];
    s16x8 fRel = {0, 0, 0, 0, 0, 0, 0, 0};
    if (cq == 0) {
      const float* xn = xyz + ((size_t)bb * N_ + nid) * 3;
      const float* xs = xyz + ((size_t)bb * N_ + idx_fps[pid0]) * 3;
      fRel[0] = (short)f2bf(xn[0] - xs[0]);
      fRel[1] = (short)f2bf(xn[1] - xs[1]);
      fRel[2] = (short)f2bf(xn[2] - xs[2]);
    }
    int g0 = cq * 2;
    *(int4*)(base + r * 128 + ((g0 ^ sw7(r)) << 4)) = pack8(f0, f1);
    *(int4*)(base + r * 128 + (((g0 + 1) ^ sw7(r)) << 4)) = pack8(f2, f3);
    #pragma unroll
    for (int ks = 0; ks < 2; ++ks)
      fAc[ks] = *(const s16x8*)(base + r * 128 + (((ks * 4 + cq) ^ sw7(r)) << 4));
    #pragma unroll
    for (int t = 0; t < 8; ++t) {
      f32x4 z = {0, 0, 0, 0};
      f32x4 c = mfma16(fRel, *(const s16x8*)((const char*)lWp1 + (16 * t + r) * 16), z);
      st16f(base, t, c, l, cq, true);
    }
  }

  // ---- pipelined per-point loop ----
  #pragma unroll 1
  for (int i = 0; i < cnt; ++i) {
    const int pid = pid0 + i;
    char* bufc = base + ((i & 1) << 12);        // holds t1(i)
    char* bufn = base + (((i + 1) & 1) << 12);  // staging target for i+1

    // 1. fT(i) reads issued
    s16x8 fT[4];
    #pragma unroll
    for (int ks = 0; ks < 4; ++ks)
      fT[ks] = *(const s16x8*)(bufc + r * 256 + (((ks * 4 + cq) ^ (r & 15)) << 4));

    // 2. vv/za on held fA (covers fT latency)
    f32x4 vv[8];
    #pragma unroll
    for (int t = 0; t < 8; ++t) vv[t] = (f32x4){0, 0, 0, 0};
    #pragma unroll
    for (int ks = 0; ks < 2; ++ks)
      #pragma unroll
      for (int t = 0; t < 8; ++t)
        vv[t] = mfma16(fAc[ks], ldw128(lWv, 16 * t + r, ks * 4 + cq), vv[t]);
    f32x4 za[2];
    za[0] = (f32x4){0, 0, 0, 0}; za[1] = (f32x4){0, 0, 0, 0};
    #pragma unroll
    for (int ks = 0; ks < 2; ++ks)
      #pragma unroll
      for (int t = 0; t < 2; ++t)
        za[t] = mfma16(fAc[ks], ldw128(lWka1, 16 * t + r, ks * 4 + cq), za[t]);

    // 3. issue gathers for point i+1 (latency hidden under step 4)
    float4 f0, f1, f2, f3;
    float rx = 0.f, ry = 0.f, rz = 0.f;
    if (i + 1 < cnt) {
      const int pidn = pid + 1;
      const int bbn = pidn >> 13;
      const int nidn = idx_knn[(size_t)pidn * K_ + r];
      const float* fn = feats + ((size_t)bbn * N_ + nidn) * CIN + cq * 16;
      f0 = ((const float4*)fn)[0]; f1 = ((const float4*)fn)[1];
      f2 = ((const float4*)fn)[2]; f3 = ((const float4*)fn)[3];
      if (cq == 0) {
        const float* xn = xyz + ((size_t)bbn * N_ + nidn) * 3;
        const float* xs = xyz + ((size_t)bbn * N_ + idx_fps[pidn]) * 3;
        rx = xn[0] - xs[0]; ry = xn[1] - xs[1]; rz = xn[2] - xs[2];
      }
    }

    // 4. fT MFMAs (40) — cover the global loads
    #pragma unroll
    for (int ks = 0; ks < 4; ++ks)
      #pragma unroll
      for (int t = 0; t < 8; ++t)
        vv[t] = mfma16(fT[ks], ldw256(lWp2, 16 * t + r, ks * 4 + cq), vv[t]);
    #pragma unroll
    for (int ks = 0; ks < 4; ++ks)
      #pragma unroll
      for (int t = 0; t < 2; ++t)
        za[t] = mfma16(fT[ks], ldw256(lWpa1, 16 * t + r, ks * 4 + cq), za[t]);

    // 5+6. consume gathers: stage nfeat(i+1), read fA(i+1), t1(i+1) -> bufn
    if (i + 1 < cnt) {
      int g0 = cq * 2;
      *(int4*)(bufn + r * 128 + ((g0 ^ sw7(r)) << 4)) = pack8(f0, f1);
      *(int4*)(bufn + r * 128 + (((g0 + 1) ^ sw7(r)) << 4)) = pack8(f2, f3);
      #pragma unroll
      for (int ks = 0; ks < 2; ++ks)
        fAc[ks] = *(const s16x8*)(bufn + r * 128 + (((ks * 4 + cq) ^ sw7(r)) << 4));
      s16x8 fRn = {0, 0, 0, 0, 0, 0, 0, 0};
      if (cq == 0) {
        fRn[0] = (short)f2bf(rx);
        fRn[1] = (short)f2bf(ry);
        fRn[2] = (short)f2bf(rz);
      }
      #pragma unroll
      for (int t = 0; t < 8; ++t) {
        f32x4 z = {0, 0, 0, 0};
        f32x4 c = mfma16(fRn, *(const s16x8*)((const char*)lWp1 + (16 * t + r) * 16), z);
        st16f(bufn, t, c, l, cq, true);   // read next iteration (fully covered)
      }
    }

    // 7. za += qa1 broadcast; relu; a1 -> bufa; ww + fused softmax
    const int ii = i & 3, iq = i >> 2;
    #pragma unroll
    for (int t = 0; t < 2; ++t) {
      float qsel = ii == 0 ? qa1[t][0] : ii == 1 ? qa1[t][1]
                 : ii == 2 ? qa1[t][2] : qa1[t][3];
      float qv = __shfl(qsel, (iq << 4) + (l & 15));
      f32x4 ta = za[t];
      #pragma unroll
      for (int rr = 0; rr < 4; ++rr) ta[rr] += qv;
      st16_a1(bufa, t, ta, l, cq);
    }
    s16x8 fA1 = *(const s16x8*)(bufa + r * 64 + ((cq ^ sw2(r)) << 4));
    #pragma unroll
    for (int t = 0; t < 8; ++t) {
      f32x4 z = {0, 0, 0, 0};
      f32x4 wwt = mfma16(fA1, fWa2[t], z);
      float m = fmaxf(fmaxf(wwt[0], wwt[1]), fmaxf(wwt[2], wwt[3]));
      m = fmaxf(m, __shfl_xor(m, 16));
      m = fmaxf(m, __shfl_xor(m, 32));
      float e0 = __expf(wwt[0] - m), e1 = __expf(wwt[1] - m);
      float e2 = __expf(wwt[2] - m), e3 = __expf(wwt[3] - m);
      float ss = e0 + e1 + e2 + e3;
      ss += __shfl_xor(ss, 16);
      ss += __shfl_xor(ss, 32);
      float acc = e0 * vv[t][0] + e1 * vv[t][1] + e2 * vv[t][2] + e3 * vv[t][3];
      acc += __shfl_xor(acc, 16);
      acc += __shfl_xor(acc, 32);
      float outv = acc / ss;
      if (cq == (t >> 2)) {
        int colp = (l & 15) + 16 * t;
        *(ushort*)((char*)g_attn + (size_t)pid * 256 + colp * 2) = f2bf(outv);
      }
    }
  }
}

// ---------------- Kernel 2: proj + res + LN + post (M = 16 points) ----------
__global__ __launch_bounds__(512, 2) void k_post(
    const float* __restrict__ Wproj, const float* __restrict__ Wres,
    const float* __restrict__ Wpost, const float* __restrict__ ln_w,
    const float* __restrict__ ln_b, float* __restrict__ out_main)
{
  __shared__ ushort lWpj[COUT * COUT];
  __shared__ ushort lWrs[COUT * CIN];
  __shared__ ushort lWps[COUT * COUT];
  __shared__ float  llnw[COUT], llnb[COUT];
  __shared__ ushort sbuf[8 * 16 * COUT];

  const int tid = threadIdx.x;
  const int w = tid >> 6, l = tid & 63;
  const int r = l & 15, cq = l >> 4;

  for (int i = tid; i < COUT * CIN; i += 512) {
    int row = i >> 6; int kp = (i & 63) * 2;
    int g = kp >> 3;
    *(uint*)((char*)lWpj + row * 256 + ((g ^ (row & 7)) << 4) + (kp & 7) * 2)
        = pk2(Wproj[row * COUT + kp], Wproj[row * COUT + kp + 1]);
  }
  for (int i = tid; i < COUT * CIN / 2; i += 512) {
    int row = i >> 5; int kp = (i & 31) * 2;
    int g = kp >> 3;
    *(uint*)((char*)lWrs + row * 128 + ((g ^ (row & 7)) << 4) + (kp & 7) * 2)
        = pk2(Wres[row * CIN + kp], Wres[row * CIN + kp + 1]);
  }
  for (int i = tid; i < COUT * CIN; i += 512) {
    int row = i >> 6; int kp = (i & 63) * 2;
    int g = kp >> 3;
    *(uint*)((char*)lWps + row * 256 + ((g ^ (row & 7)) << 4) + (kp & 7) * 2)
        = pk2(Wpost[row * COUT + kp], Wpost[row * COUT + kp + 1]);
  }
  if (tid < COUT) { llnw[tid] = ln_w[tid]; llnb[tid] = ln_b[tid]; }
  __syncthreads();

  const int T = blockIdx.x * 8 + w;     // 16-point tile id
  char* bufb = (char*)(sbuf + w * 16 * COUT);

  f32x4 acc[8];
  #pragma unroll
  for (int t = 0; t < 8; ++t) acc[t] = (f32x4){0, 0, 0, 0};

  s16x8 fA[4];
  #pragma unroll
  for (int ks = 0; ks < 4; ++ks)
    fA[ks] = *(const s16x8*)(g_attn + ((size_t)T * 16 + r) * COUT + ks * 32 + cq * 8);
  #pragma unroll
  for (int ks = 0; ks < 4; ++ks)
    #pragma unroll
    for (int t = 0; t < 8; ++t)
      acc[t] = mfma16(fA[ks], ldw256(lWpj, 16 * t + r, ks * 4 + cq), acc[t]);

  s16x8 fS[2];
  #pragma unroll
  for (int ks = 0; ks < 2; ++ks)
    fS[ks] = *(const s16x8*)(g_sfeat + ((size_t)T * 16 + r) * CIN + ks * 32 + cq * 8);
  #pragma unroll
  for (int ks = 0; ks < 2; ++ks)
    #pragma unroll
    for (int t = 0; t < 8; ++t)
      acc[t] = mfma16(fS[ks], ldw128(lWrs, 16 * t + r, ks * 4 + cq), acc[t]);

  // LayerNorm per row (= point)
  #pragma unroll
  for (int rr = 0; rr < 4; ++rr) {
    float s1 = 0.f, s2 = 0.f;
    #pragma unroll
    for (int t = 0; t < 8; ++t) { float v = acc[t][rr]; s1 += v; s2 += v * v; }
    #pragma unroll
    for (int off = 1; off < 16; off <<= 1) {
      s1 += __shfl_xor(s1, off);
      s2 += __shfl_xor(s2, off);
    }
    float mu = s1 * (1.f / COUT);
    float rs = rsqrtf(s2 * (1.f / COUT) - mu * mu + EPS_);
    #pragma unroll
    for (int t = 0; t < 8; ++t) {
      int col = (l & 15) + 16 * t;
      acc[t][rr] = (acc[t][rr] - mu) * rs * llnw[col] + llnb[col];
    }
  }
  #pragma unroll
  for (int t = 0; t < 8; ++t) st16p(bufb, t, acc[t], l, cq);

  // post conv GEMM (fZ reads match st16p's row&15 swizzle)
  s16x8 fZ[4];
  #pragma unroll
  for (int ks = 0; ks < 4; ++ks)
    fZ[ks] = *(const s16x8*)(bufb + r * 256 + (((ks * 4 + cq) ^ (r & 15)) << 4));
  f32x4 po[8];
  #pragma unroll
  for (int t = 0; t < 8; ++t) po[t] = (f32x4){0, 0, 0, 0};
  #pragma unroll
  for (int ks = 0; ks < 4; ++ks)
    #pragma unroll
    for (int t = 0; t < 8; ++t)
      po[t] = mfma16(fZ[ks], ldw256(lWps, 16 * t + r, ks * 4 + cq), po[t]);

  // write pre-GN post + per-tile GN partials (group = tile t)
  #pragma unroll
  for (int t = 0; t < 8; ++t) {
    float s1 = po[t][0] + po[t][1] + po[t][2] + po[t][3];
    float s2 = po[t][0] * po[t][0] + po[t][1] * po[t][1]
             + po[t][2] * po[t][2] + po[t][3] * po[t][3];
    #pragma unroll
    for (int off = 1; off < 64; off <<= 1) {
      s1 += __shfl_xor(s1, off);
      s2 += __shfl_xor(s2, off);
    }
    if (l == 0) {
      g_part[((size_t)T * 8 + t) * 2] = s1;
      g_part[((size_t)T * 8 + t) * 2 + 1] = s2;
    }
    #pragma unroll
    for (int rr = 0; rr < 4; ++rr) {
      int row = T * 16 + cq * 4 + rr;
      out_main[(size_t)row * COUT + (l & 15) + 16 * t] = po[t][rr];
    }
  }
}

// ---------------- GroupNorm finish + apply ----------------------------------
__global__ void k_gn_finish(void) {
  int bg = blockIdx.x;          // 0..31  (b*8+g)
  int b = bg >> 3, g = bg & 7;
  int t = threadIdx.x;          // 64
  float s1 = 0.f, s2 = 0.f;
  for (int i = t; i < 512; i += 64) {
    size_t T = (size_t)b * 512 + i;
    s1 += g_part[(T * 8 + g) * 2];
    s2 += g_part[(T * 8 + g) * 2 + 1];
  }
  #pragma unroll
  for (int off = 1; off < 64; off <<= 1) {
    s1 += __shfl_xor(s1, off);
    s2 += __shfl_xor(s2, off);
  }
  if (t == 0) {
    float n = (float)S_ * 16.f;
    float mu = s1 / n;
    float var = s2 / n - mu * mu;
    g_stats[bg * 2] = mu;
    g_stats[bg * 2 + 1] = rsqrtf(var + EPS_);
  }
}

__global__ __launch_bounds__(256) void k_gn_apply(
    float* __restrict__ x, const float* __restrict__ gn_w,
    const float* __restrict__ gn_b)
{
  const int i = blockIdx.x * 256 + threadIdx.x;   // float4 index
  if (i >= B_ * S_ * (COUT / 4)) return;
  const int c = (i & 31) * 4;
  const int g = c >> 4;
  const int b = i >> 18;
  const float m = g_stats[(b * 8 + g) * 2];
  const float rv = g_stats[(b * 8 + g) * 2 + 1];
  float4 v = ((float4*)x)[i];
  v.x = fmaxf((v.x - m) * rv * gn_w[c + 0] + gn_b[c + 0], 0.f);
  v.y = fmaxf((v.y - m) * rv * gn_w[c + 1] + gn_b[c + 1], 0.f);
  v.z = fmaxf((v.z - m) * rv * gn_w[c + 2] + gn_b[c + 2], 0.f);
  v.w = fmaxf((v.w - m) * rv * gn_w[c + 3] + gn_b[c + 3], 0.f);
  ((float4*)x)[i] = v;
}

extern "C" void kernel_launch(void* const* d_in, const int* in_sizes, int n_in,
                              void* d_out, int out_size, void* d_ws, size_t ws_size,
                              hipStream_t stream) {
  const float* xyz     = (const float*)d_in[0];
  const float* feats   = (const float*)d_in[1];
  const int*   idx_fps = (const int*)d_in[2];
  const int*   idx_knn = (const int*)d_in[3];
  const float* Wq    = (const float*)d_in[4];
  const float* Wk    = (const float*)d_in[5];
  const float* Wv    = (const float*)d_in[6];
  const float* Wp1   = (const float*)d_in[7];
  const float* Wp2   = (const float*)d_in[8];
  const float* Wa1   = (const float*)d_in[9];
  const float* Wa2   = (const float*)d_in[10];
  const float* Wproj = (const float*)d_in[11];
  const float* ln_w  = (const float*)d_in[12];
  const float* ln_b  = (const float*)d_in[13];
  const float* Wres  = (const float*)d_in[14];
  const float* Wpost = (const float*)d_in[15];
  const float* gn_w  = (const float*)d_in[16];
  const float* gn_b  = (const float*)d_in[17];

  float* out      = (float*)d_out;
  float* out_xyz  = out;
  float* out_main = out + (size_t)B_ * S_ * 3;

  k_fuse<<<dim3(32), dim3(256), 0, stream>>>(Wq, Wk, Wp2, Wa1);
  k_attn<<<dim3(256), dim3(640), 0, stream>>>(
      xyz, feats, idx_fps, idx_knn, Wv, Wp1, Wp2, Wa2, out_xyz);
  k_post<<<dim3(256), dim3(512), 0, stream>>>(
      Wproj, Wres, Wpost, ln_w, ln_b, out_main);
  k_gn_finish<<<dim3(32), dim3(64), 0, stream>>>();
  k_gn_apply<<<dim3((B_ * S_ * (COUT / 4) + 255) / 256), dim3(256), 0, stream>>>(
      out_main, gn_w, gn_b);
}

// Round 16
// 144.418 us; speedup vs baseline: 4.8168x; 4.8168x over previous
//
#include <hip/hip_runtime.h>
#include <hip/hip_bf16.h>
#include <math.h>

#define B_ 4
#define N_ 32768
#define S_ 8192
#define K_ 16
#define CIN 64
#define COUT 128
#define MID_ 32
#define EPS_ 1e-5f
#define NTILE 2048   // (B_*S_)/16 epilogue tiles

typedef __attribute__((ext_vector_type(8))) short s16x8;
typedef __attribute__((ext_vector_type(4))) float f32x4;

// static scratch (written fully every call before being read)
__device__ ushort g_attn[(size_t)B_ * S_ * COUT];   // attn output, bf16, row-major
__device__ ushort g_sfeat[(size_t)B_ * S_ * CIN];   // gathered s_feat, bf16
__device__ float  g_part[NTILE * 8 * 2];            // GN partial sums per tile/group
__device__ float  g_stats[64];                      // GN mean/rstd per (b,g)
// fused weights: [0,2048) Wqa1 32x64; [2048,4096) Wka1 32x64; [4096,8192) Wpa1 32x128
__device__ float  g_fw[8192];

// hardware bf16 converts (v_cvt_pk_bf16_f32)
__device__ __forceinline__ uint pk2(float lo, float hi) {
  __hip_bfloat162 h = __float22bfloat162_rn(make_float2(lo, hi));
  return *(uint*)&h;
}
__device__ __forceinline__ ushort f2bf(float f) {
  __hip_bfloat16 h = __float2bfloat16(f);
  return *(ushort*)&h;
}
__device__ __forceinline__ int4 pack8(float4 a, float4 b) {
  int4 o;
  o.x = pk2(a.x, a.y); o.y = pk2(a.z, a.w);
  o.z = pk2(b.x, b.y); o.w = pk2(b.z, b.w);
  return o;
}
__device__ __forceinline__ f32x4 mfma16(s16x8 a, s16x8 b, f32x4 c) {
  return __builtin_amdgcn_mfma_f32_16x16x32_bf16(a, b, c, 0, 0, 0);
}
__device__ __forceinline__ int sw7(int row) { return (row & 7) ^ ((row & 8) >> 2); }
__device__ __forceinline__ int sw2(int row) { return (row & 3) ^ ((row >> 2) & 3); }

// weight B-frag reads, swizzled rows of 256B / 128B
__device__ __forceinline__ s16x8 ldw256(const ushort* W, int row, int g) {
  return *(const s16x8*)((const char*)W + row * 256 + ((g ^ (row & 7)) << 4));
}
__device__ __forceinline__ s16x8 ldw128(const ushort* W, int row, int g) {
  return *(const s16x8*)((const char*)W + row * 128 + ((g ^ (row & 7)) << 4));
}
__device__ __forceinline__ s16x8 ldfrag_g8(const float* p) {
  float4 a = *(const float4*)p, b = *(const float4*)(p + 4);
  union { int4 i; s16x8 s; } u;
  u.i = pack8(a, b);
  return u.s;
}
// store a 16x64 half C tile (tiles t=0..3) into 128B-row sw7 buffer
__device__ __forceinline__ void st16h(char* bufb, int t, f32x4 c, int l, int cq,
                                      bool dorelu) {
  const int colp = (l & 15) + 16 * t;   // 0..63
  const int g = colp >> 3;              // 0..7
  const int off = (colp & 7) * 2;
  #pragma unroll
  for (int rr = 0; rr < 4; ++rr) {
    const int row = cq * 4 + rr;
    float v = dorelu ? fmaxf(c[rr], 0.f) : c[rr];
    *(ushort*)(bufb + row * 128 + ((g ^ sw7(row)) << 4) + off) = f2bf(v);
  }
}
// store 16x32 a1 tile (row stride 64B, sw2) with relu, b16 writes
__device__ __forceinline__ void st16_a1(char* bufb, int t, f32x4 c, int l, int cq) {
  const int colp = (l & 15) + 16 * t;   // 0..31
  const int g = colp >> 3;              // 0..3
  const int off = (colp & 7) * 2;
  #pragma unroll
  for (int rr = 0; rr < 4; ++rr) {
    const int row = cq * 4 + rr;
    *(ushort*)(bufb + row * 64 + ((g ^ sw2(row)) << 4) + off) =
        f2bf(fmaxf(c[rr], 0.f));
  }
}
// k_post: 256B-row sbuf store with full row&15 spread
__device__ __forceinline__ void st16p(char* bufb, int t, f32x4 c, int l, int cq) {
  const int colp = (l & 15) + 16 * t;
  const int g = colp >> 3;
  const int off = (colp & 7) * 2;
  #pragma unroll
  for (int rr = 0; rr < 4; ++rr) {
    const int row = cq * 4 + rr;
    *(ushort*)(bufb + row * 256 + ((g ^ (row & 15)) << 4) + off) = f2bf(c[rr]);
  }
}

// ---------------- Kernel 0: fused weights  Wa1 @ {Wq, Wk, Wp2} ---------------
__global__ __launch_bounds__(256) void k_fuse(
    const float* __restrict__ Wq, const float* __restrict__ Wk,
    const float* __restrict__ Wp2, const float* __restrict__ Wa1)
{
  const int t = blockIdx.x * 256 + threadIdx.x;   // 0..8191
  if (t < 2048) {
    int m = t >> 6, c = t & 63;
    float s = 0.f;
    for (int o = 0; o < COUT; ++o) s += Wa1[m * COUT + o] * Wq[o * CIN + c];
    g_fw[t] = s;
  } else if (t < 4096) {
    int u = t - 2048;
    int m = u >> 6, c = u & 63;
    float s = 0.f;
    for (int o = 0; o < COUT; ++o) s += Wa1[m * COUT + o] * Wk[o * CIN + c];
    g_fw[t] = s;
  } else {
    int u = t - 4096;
    int m = u >> 7, c = u & 127;
    float s = 0.f;
    for (int o = 0; o < COUT; ++o) s += Wa1[m * COUT + o] * Wp2[o * COUT + c];
    g_fw[t] = s;
  }
}

// --- Kernel 1: attention core (512 thr x 2 blocks/CU target, za-first) ------
// LDS: 16K lWv + 2K lWp1 + 32K lWp2 + 4K lWka1 + 8K lWpa1 + 16K sbuf = 79872 B
// -> 2 blocks/CU LDS-feasible (159744 <= 163840).
// Register plan: hold fT0+fT1 (K=128 of t1); compute za FIRST (12 MFMAs),
// then per output tile t: vv_t (6 MFMAs) + ww_t + fused softmax. Acc peak
// drops ~52 -> ~16, so per-wave total ~112 <= 128 -> 4 waves/SIMD pool-legal.
__global__ __launch_bounds__(512, 2) void k_attn(
    const float* __restrict__ xyz, const float* __restrict__ feats,
    const int* __restrict__ idx_fps, const int* __restrict__ idx_knn,
    const float* __restrict__ Wv, const float* __restrict__ Wp1,
    const float* __restrict__ Wp2, const float* __restrict__ Wa2,
    float* __restrict__ out_xyz)
{
  __shared__ ushort lWv[COUT * CIN];     // 16 KB, 128B rows swz
  __shared__ ushort lWp1[COUT * 8];      // 2 KB, 16B rows linear
  __shared__ ushort lWp2[COUT * COUT];   // 32 KB, 256B rows swz
  __shared__ ushort lWka1[MID_ * CIN];   // 4 KB, 128B rows swz (holds -Wka1)
  __shared__ ushort lWpa1[MID_ * COUT];  // 8 KB, 256B rows swz
  __shared__ ushort sbuf[8 * 1024];      // per wave 2KB: nfeat -> t1h1 -> t1h2 -> a1

  const int tid = threadIdx.x;
  const int w = tid >> 6, l = tid & 63;
  const int r = l & 15, cq = l >> 4;

  for (int i = tid; i < COUT * CIN / 2; i += 512) {
    int row = i >> 5; int kp = (i & 31) * 2;
    int g = kp >> 3;
    *(uint*)((char*)lWv + row * 128 + ((g ^ (row & 7)) << 4) + (kp & 7) * 2)
        = pk2(Wv[row * CIN + kp], Wv[row * CIN + kp + 1]);
  }
  { // Wp1 padded: 128 rows x 4 pairs = 512
    int row = tid >> 2; int kp = (tid & 3) * 2;
    float lo = (kp < 3) ? Wp1[row * 3 + kp] : 0.f;
    float hi = (kp + 1 < 3) ? Wp1[row * 3 + kp + 1] : 0.f;
    *(uint*)((char*)lWp1 + row * 16 + kp * 2) = pk2(lo, hi);
  }
  for (int i = tid; i < COUT * CIN; i += 512) {
    int row = i >> 6; int kp = (i & 63) * 2;
    int g = kp >> 3;
    *(uint*)((char*)lWp2 + row * 256 + ((g ^ (row & 7)) << 4) + (kp & 7) * 2)
        = pk2(Wp2[row * COUT + kp], Wp2[row * COUT + kp + 1]);
  }
  for (int i = tid; i < MID_ * CIN / 2; i += 512) {   // -Wka1
    int row = i >> 5; int kp = (i & 31) * 2;
    int g = kp >> 3;
    const float* src = g_fw + 2048 + row * CIN + kp;
    *(uint*)((char*)lWka1 + row * 128 + ((g ^ (row & 7)) << 4) + (kp & 7) * 2)
        = pk2(-src[0], -src[1]);
  }
  for (int i = tid; i < MID_ * COUT / 2; i += 512) {  // Wpa1
    int row = i >> 6; int kp = (i & 63) * 2;
    int g = kp >> 3;
    const float* src = g_fw + 4096 + row * COUT + kp;
    *(uint*)((char*)lWpa1 + row * 256 + ((g ^ (row & 7)) << 4) + (kp & 7) * 2)
        = pk2(src[0], src[1]);
  }

  // register-resident Wa2 B-frags (8 n-tiles, 32 VGPR)
  s16x8 fWa2[8];
  #pragma unroll
  for (int t = 0; t < 8; ++t)
    fWa2[t] = ldfrag_g8(Wa2 + (16 * t + r) * MID_ + cq * 8);

  __syncthreads();

  char* bufb = (char*)(sbuf + w * 1024);        // 2 KB
  const int pid0 = (blockIdx.x * 8 + w) * 8;    // 8 points per wave

  // ---- prologue: stage sfeat (rows 0-7 = points, 8-15 dup), qa1 GEMM ----
  {
    const int p = pid0 + (r & 7);
    const int bb = p >> 13;
    const int si = idx_fps[p];
    const float* fs = feats + ((size_t)bb * N_ + si) * CIN;
    #pragma unroll
    for (int j = 0; j < 2; ++j) {
      int g = cq * 2 + j;
      int4 pks = pack8(*(const float4*)(fs + g * 8), *(const float4*)(fs + g * 8 + 4));
      *(int4*)(bufb + r * 128 + ((g ^ sw7(r)) << 4)) = pks;
      if (r < 8) *(int4*)((char*)g_sfeat + (size_t)p * 128 + g * 16) = pks;
    }
    if (l < 24) {
      int pi = l / 3, j = l - pi * 3;
      int pp = pid0 + pi;
      out_xyz[(size_t)pp * 3 + j] =
          xyz[((size_t)(pp >> 13) * N_ + idx_fps[pp]) * 3 + j];
    }
  }
  f32x4 qa1[2];
  qa1[0] = (f32x4){0, 0, 0, 0}; qa1[1] = (f32x4){0, 0, 0, 0};
  {
    s16x8 fS[2], fQ;
    #pragma unroll
    for (int ks = 0; ks < 2; ++ks)
      fS[ks] = *(const s16x8*)(bufb + r * 128 + (((ks * 4 + cq) ^ sw7(r)) << 4));
    #pragma unroll
    for (int ks = 0; ks < 2; ++ks)
      #pragma unroll
      for (int t = 0; t < 2; ++t) {
        fQ = ldfrag_g8(g_fw + (16 * t + r) * CIN + ks * 32 + cq * 8);
        qa1[t] = mfma16(fS[ks], fQ, qa1[t]);
      }
  }

  // ---- per-point loop (gather in-loop; 16 waves/CU of TLP hides latency) ----
  #pragma unroll 1
  for (int i = 0; i < 8; ++i) {
    const int pid = pid0 + i;
    const int bb = pid >> 13;
    const int nid = idx_knn[(size_t)pid * K_ + r];
    const float* fn = feats + ((size_t)bb * N_ + nid) * CIN + cq * 16;
    float4 f0 = ((const float4*)fn)[0], f1 = ((const float4*)fn)[1];
    float4 f2 = ((const float4*)fn)[2], f3 = ((const float4*)fn)[3];

    s16x8 fRel = {0, 0, 0, 0, 0, 0, 0, 0};
    if (cq == 0) {
      const float* xn = xyz + ((size_t)bb * N_ + nid) * 3;
      const float* xs = xyz + ((size_t)bb * N_ + idx_fps[pid]) * 3;
      fRel[0] = (short)f2bf(xn[0] - xs[0]);
      fRel[1] = (short)f2bf(xn[1] - xs[1]);
      fRel[2] = (short)f2bf(xn[2] - xs[2]);
    }

    // stage nfeat (16 x 64 bf16, 128B sw7 rows)
    {
      int g0 = cq * 2;
      *(int4*)(bufb + r * 128 + ((g0 ^ sw7(r)) << 4)) = pack8(f0, f1);
      *(int4*)(bufb + r * 128 + (((g0 + 1) ^ sw7(r)) << 4)) = pack8(f2, f3);
    }

    // A-frags of staged nfeat (read BEFORE t1h1 overwrites the buffer)
    s16x8 fA[2];
    #pragma unroll
    for (int ks = 0; ks < 2; ++ks)
      fA[ks] = *(const s16x8*)(bufb + r * 128 + (((ks * 4 + cq) ^ sw7(r)) << 4));

    // t1 half1 = relu(rel @ Wp1^T), tiles 0..3 -> buf (overwrites nfeat)
    #pragma unroll
    for (int t = 0; t < 4; ++t) {
      f32x4 z = {0, 0, 0, 0};
      f32x4 c = mfma16(fRel, *(const s16x8*)((const char*)lWp1 + (16 * t + r) * 16), z);
      st16h(bufb, t, c, l, cq, true);
    }

    // za phase A: fA x lWka1 (covers t1h1 store->read)
    f32x4 za[2];
    za[0] = (f32x4){0, 0, 0, 0}; za[1] = (f32x4){0, 0, 0, 0};
    #pragma unroll
    for (int ks = 0; ks < 2; ++ks)
      #pragma unroll
      for (int t = 0; t < 2; ++t)
        za[t] = mfma16(fA[ks], ldw128(lWka1, 16 * t + r, ks * 4 + cq), za[t]);

    // read t1 half1 A-frags (k = 0..63) — HELD through the tile loop
    s16x8 fT0[2];
    #pragma unroll
    for (int ks = 0; ks < 2; ++ks)
      fT0[ks] = *(const s16x8*)(bufb + r * 128 + (((ks * 4 + cq) ^ sw7(r)) << 4));

    // t1 half2, tiles 4..7 -> buf (overwrites half1)
    #pragma unroll
    for (int t = 0; t < 4; ++t) {
      f32x4 z = {0, 0, 0, 0};
      f32x4 c = mfma16(fRel,
                       *(const s16x8*)((const char*)lWp1 + (16 * (t + 4) + r) * 16), z);
      st16h(bufb, t, c, l, cq, true);
    }

    // za phase B: fT0 x lWpa1 (k-cols 0..63) — covers t1h2 store->read
    #pragma unroll
    for (int ks = 0; ks < 2; ++ks)
      #pragma unroll
      for (int t = 0; t < 2; ++t)
        za[t] = mfma16(fT0[ks], ldw256(lWpa1, 16 * t + r, ks * 4 + cq), za[t]);

    // read t1 half2 A-frags (k = 64..127) — HELD through the tile loop
    s16x8 fT1[2];
    #pragma unroll
    for (int ks = 0; ks < 2; ++ks)
      fT1[ks] = *(const s16x8*)(bufb + r * 128 + (((ks * 4 + cq) ^ sw7(r)) << 4));

    // za phase C: fT1 x lWpa1 (k-cols 64..127)
    #pragma unroll
    for (int ks = 0; ks < 2; ++ks)
      #pragma unroll
      for (int t = 0; t < 2; ++t)
        za[t] = mfma16(fT1[ks], ldw256(lWpa1, 16 * t + r, (ks + 2) * 4 + cq), za[t]);

    // za += qa1 broadcast; relu; a1 -> buf (fT1 reads already issued)
    const int ii = i & 3, iq = i >> 2;
    #pragma unroll
    for (int t = 0; t < 2; ++t) {
      float qsel = ii == 0 ? qa1[t][0] : ii == 1 ? qa1[t][1]
                 : ii == 2 ? qa1[t][2] : qa1[t][3];
      float qv = __shfl(qsel, (iq << 4) + (l & 15));
      f32x4 ta = za[t];
      #pragma unroll
      for (int rr = 0; rr < 4; ++rr) ta[rr] += qv;
      st16_a1(bufb, t, ta, l, cq);
    }
    s16x8 fA1 = *(const s16x8*)(bufb + r * 64 + ((cq ^ sw2(r)) << 4));

    // per-output-tile: vv_t (6 MFMAs) + ww_t + fused softmax + write
    #pragma unroll
    for (int t = 0; t < 8; ++t) {
      f32x4 vt = {0, 0, 0, 0};
      #pragma unroll
      for (int ks = 0; ks < 2; ++ks)
        vt = mfma16(fA[ks], ldw128(lWv, 16 * t + r, ks * 4 + cq), vt);
      #pragma unroll
      for (int ks = 0; ks < 2; ++ks)
        vt = mfma16(fT0[ks], ldw256(lWp2, 16 * t + r, ks * 4 + cq), vt);
      #pragma unroll
      for (int ks = 0; ks < 2; ++ks)
        vt = mfma16(fT1[ks], ldw256(lWp2, 16 * t + r, (ks + 2) * 4 + cq), vt);
      f32x4 z = {0, 0, 0, 0};
      f32x4 wwt = mfma16(fA1, fWa2[t], z);
      float m = fmaxf(fmaxf(wwt[0], wwt[1]), fmaxf(wwt[2], wwt[3]));
      m = fmaxf(m, __shfl_xor(m, 16));
      m = fmaxf(m, __shfl_xor(m, 32));
      float e0 = __expf(wwt[0] - m), e1 = __expf(wwt[1] - m);
      float e2 = __expf(wwt[2] - m), e3 = __expf(wwt[3] - m);
      float ss = e0 + e1 + e2 + e3;
      ss += __shfl_xor(ss, 16);
      ss += __shfl_xor(ss, 32);
      float acc = e0 * vt[0] + e1 * vt[1] + e2 * vt[2] + e3 * vt[3];
      acc += __shfl_xor(acc, 16);
      acc += __shfl_xor(acc, 32);
      float outv = acc / ss;
      if (cq == (t >> 2)) {
        int colp = (l & 15) + 16 * t;
        *(ushort*)((char*)g_attn + (size_t)pid * 256 + colp * 2) = f2bf(outv);
      }
    }
  }
}

// ---------------- Kernel 2: proj + res + LN + post (M = 16 points) ----------
__global__ __launch_bounds__(512, 2) void k_post(
    const float* __restrict__ Wproj, const float* __restrict__ Wres,
    const float* __restrict__ Wpost, const float* __restrict__ ln_w,
    const float* __restrict__ ln_b, float* __restrict__ out_main)
{
  __shared__ ushort lWpj[COUT * COUT];
  __shared__ ushort lWrs[COUT * CIN];
  __shared__ ushort lWps[COUT * COUT];
  __shared__ float  llnw[COUT], llnb[COUT];
  __shared__ ushort sbuf[8 * 16 * COUT];

  const int tid = threadIdx.x;
  const int w = tid >> 6, l = tid & 63;
  const int r = l & 15, cq = l >> 4;

  for (int i = tid; i < COUT * CIN; i += 512) {
    int row = i >> 6; int kp = (i & 63) * 2;
    int g = kp >> 3;
    *(uint*)((char*)lWpj + row * 256 + ((g ^ (row & 7)) << 4) + (kp & 7) * 2)
        = pk2(Wproj[row * COUT + kp], Wproj[row * COUT + kp + 1]);
  }
  for (int i = tid; i < COUT * CIN / 2; i += 512) {
    int row = i >> 5; int kp = (i & 31) * 2;
    int g = kp >> 3;
    *(uint*)((char*)lWrs + row * 128 + ((g ^ (row & 7)) << 4) + (kp & 7) * 2)
        = pk2(Wres[row * CIN + kp], Wres[row * CIN + kp + 1]);
  }
  for (int i = tid; i < COUT * CIN; i += 512) {
    int row = i >> 6; int kp = (i & 63) * 2;
    int g = kp >> 3;
    *(uint*)((char*)lWps + row * 256 + ((g ^ (row & 7)) << 4) + (kp & 7) * 2)
        = pk2(Wpost[row * COUT + kp], Wpost[row * COUT + kp + 1]);
  }
  if (tid < COUT) { llnw[tid] = ln_w[tid]; llnb[tid] = ln_b[tid]; }
  __syncthreads();

  const int T = blockIdx.x * 8 + w;     // 16-point tile id
  char* bufb = (char*)(sbuf + w * 16 * COUT);

  f32x4 acc[8];
  #pragma unroll
  for (int t = 0; t < 8; ++t) acc[t] = (f32x4){0, 0, 0, 0};

  s16x8 fA[4];
  #pragma unroll
  for (int ks = 0; ks < 4; ++ks)
    fA[ks] = *(const s16x8*)(g_attn + ((size_t)T * 16 + r) * COUT + ks * 32 + cq * 8);
  #pragma unroll
  for (int ks = 0; ks < 4; ++ks)
    #pragma unroll
    for (int t = 0; t < 8; ++t)
      acc[t] = mfma16(fA[ks], ldw256(lWpj, 16 * t + r, ks * 4 + cq), acc[t]);

  s16x8 fS[2];
  #pragma unroll
  for (int ks = 0; ks < 2; ++ks)
    fS[ks] = *(const s16x8*)(g_sfeat + ((size_t)T * 16 + r) * CIN + ks * 32 + cq * 8);
  #pragma unroll
  for (int ks = 0; ks < 2; ++ks)
    #pragma unroll
    for (int t = 0; t < 8; ++t)
      acc[t] = mfma16(fS[ks], ldw128(lWrs, 16 * t + r, ks * 4 + cq), acc[t]);

  // LayerNorm per row (= point)
  #pragma unroll
  for (int rr = 0; rr < 4; ++rr) {
    float s1 = 0.f, s2 = 0.f;
    #pragma unroll
    for (int t = 0; t < 8; ++t) { float v = acc[t][rr]; s1 += v; s2 += v * v; }
    #pragma unroll
    for (int off = 1; off < 16; off <<= 1) {
      s1 += __shfl_xor(s1, off);
      s2 += __shfl_xor(s2, off);
    }
    float mu = s1 * (1.f / COUT);
    float rs = rsqrtf(s2 * (1.f / COUT) - mu * mu + EPS_);
    #pragma unroll
    for (int t = 0; t < 8; ++t) {
      int col = (l & 15) + 16 * t;
      acc[t][rr] = (acc[t][rr] - mu) * rs * llnw[col] + llnb[col];
    }
  }
  #pragma unroll
  for (int t = 0; t < 8; ++t) st16p(bufb, t, acc[t], l, cq);

  // post conv GEMM (fZ reads match st16p's row&15 swizzle)
  s16x8 fZ[4];
  #pragma unroll
  for (int ks = 0; ks < 4; ++ks)
    fZ[ks] = *(const s16x8*)(bufb + r * 256 + (((ks * 4 + cq) ^ (r & 15)) << 4));
  f32x4 po[8];
  #pragma unroll
  for (int t = 0; t < 8; ++t) po[t] = (f32x4){0, 0, 0, 0};
  #pragma unroll
  for (int ks = 0; ks < 4; ++ks)
    #pragma unroll
    for (int t = 0; t < 8; ++t)
      po[t] = mfma16(fZ[ks], ldw256(lWps, 16 * t + r, ks * 4 + cq), po[t]);

  // write pre-GN post + per-tile GN partials (group = tile t)
  #pragma unroll
  for (int t = 0; t < 8; ++t) {
    float s1 = po[t][0] + po[t][1] + po[t][2] + po[t][3];
    float s2 = po[t][0] * po[t][0] + po[t][1] * po[t][1]
             + po[t][2] * po[t][2] + po[t][3] * po[t][3];
    #pragma unroll
    for (int off = 1; off < 64; off <<= 1) {
      s1 += __shfl_xor(s1, off);
      s2 += __shfl_xor(s2, off);
    }
    if (l == 0) {
      g_part[((size_t)T * 8 + t) * 2] = s1;
      g_part[((size_t)T * 8 + t) * 2 + 1] = s2;
    }
    #pragma unroll
    for (int rr = 0; rr < 4; ++rr) {
      int row = T * 16 + cq * 4 + rr;
      out_main[(size_t)row * COUT + (l & 15) + 16 * t] = po[t][rr];
    }
  }
}

// ---------------- GroupNorm finish + apply ----------------------------------
__global__ void k_gn_finish(void) {
  int bg = blockIdx.x;          // 0..31  (b*8+g)
  int b = bg >> 3, g = bg & 7;
  int t = threadIdx.x;          // 64
  float s1 = 0.f, s2 = 0.f;
  for (int i = t; i < 512; i += 64) {
    size_t T = (size_t)b * 512 + i;
    s1 += g_part[(T * 8 + g) * 2];
    s2 += g_part[(T * 8 + g) * 2 + 1];
  }
  #pragma unroll
  for (int off = 1; off < 64; off <<= 1) {
    s1 += __shfl_xor(s1, off);
    s2 += __shfl_xor(s2, off);
  }
  if (t == 0) {
    float n = (float)S_ * 16.f;
    float mu = s1 / n;
    float var = s2 / n - mu * mu;
    g_stats[bg * 2] = mu;
    g_stats[bg * 2 + 1] = rsqrtf(var + EPS_);
  }
}

__global__ __launch_bounds__(256) void k_gn_apply(
    float* __restrict__ x, const float* __restrict__ gn_w,
    const float* __restrict__ gn_b)
{
  const int i = blockIdx.x * 256 + threadIdx.x;   // float4 index
  if (i >= B_ * S_ * (COUT / 4)) return;
  const int c = (i & 31) * 4;
  const int g = c >> 4;
  const int b = i >> 18;
  const float m = g_stats[(b * 8 + g) * 2];
  const float rv = g_stats[(b * 8 + g) * 2 + 1];
  float4 v = ((float4*)x)[i];
  v.x = fmaxf((v.x - m) * rv * gn_w[c + 0] + gn_b[c + 0], 0.f);
  v.y = fmaxf((v.y - m) * rv * gn_w[c + 1] + gn_b[c + 1], 0.f);
  v.z = fmaxf((v.z - m) * rv * gn_w[c + 2] + gn_b[c + 2], 0.f);
  v.w = fmaxf((v.w - m) * rv * gn_w[c + 3] + gn_b[c + 3], 0.f);
  ((float4*)x)[i] = v;
}

extern "C" void kernel_launch(void* const* d_in, const int* in_sizes, int n_in,
                              void* d_out, int out_size, void* d_ws, size_t ws_size,
                              hipStream_t stream) {
  const float* xyz     = (const float*)d_in[0];
  const float* feats   = (const float*)d_in[1];
  const int*   idx_fps = (const int*)d_in[2];
  const int*   idx_knn = (const int*)d_in[3];
  const float* Wq    = (const float*)d_in[4];
  const float* Wk    = (const float*)d_in[5];
  const float* Wv    = (const float*)d_in[6];
  const float* Wp1   = (const float*)d_in[7];
  const float* Wp2   = (const float*)d_in[8];
  const float* Wa1   = (const float*)d_in[9];
  const float* Wa2   = (const float*)d_in[10];
  const float* Wproj = (const float*)d_in[11];
  const float* ln_w  = (const float*)d_in[12];
  const float* ln_b  = (const float*)d_in[13];
  const float* Wres  = (const float*)d_in[14];
  const float* Wpost = (const float*)d_in[15];
  const float* gn_w  = (const float*)d_in[16];
  const float* gn_b  = (const float*)d_in[17];

  float* out      = (float*)d_out;
  float* out_xyz  = out;
  float* out_main = out + (size_t)B_ * S_ * 3;

  k_fuse<<<dim3(32), dim3(256), 0, stream>>>(Wq, Wk, Wp2, Wa1);
  k_attn<<<dim3(512), dim3(512), 0, stream>>>(
      xyz, feats, idx_fps, idx_knn, Wv, Wp1, Wp2, Wa2, out_xyz);
  k_post<<<dim3(256), dim3(512), 0, stream>>>(
      Wproj, Wres, Wpost, ln_w, ln_b, out_main);
  k_gn_finish<<<dim3(32), dim3(64), 0, stream>>>();
  k_gn_apply<<<dim3((B_ * S_ * (COUT / 4) + 255) / 256), dim3(256), 0, stream>>>(
      out_main, gn_w, gn_b);
}

// Round 17
// 121.627 us; speedup vs baseline: 5.7194x; 1.1874x over previous
//
#include <hip/hip_runtime.h>
#include <hip/hip_bf16.h>
#include <math.h>

#define B_ 4
#define N_ 32768
#define S_ 8192
#define K_ 16
#define CIN 64
#define COUT 128
#define MID_ 32
#define EPS_ 1e-5f
#define NTILE 2048   // (B_*S_)/16 epilogue tiles

typedef __attribute__((ext_vector_type(8))) short s16x8;
typedef __attribute__((ext_vector_type(4))) float f32x4;

// static scratch (written fully every call before being read)
__device__ ushort g_attn[(size_t)B_ * S_ * COUT];   // attn output, bf16, row-major
__device__ ushort g_sfeat[(size_t)B_ * S_ * CIN];   // gathered s_feat, bf16
__device__ float  g_part[NTILE * 8 * 2];            // GN partial sums per tile/group
__device__ float  g_stats[64];                      // GN mean/rstd per (b,g)
// fused weights: [0,2048) Wqa1 32x64; [2048,4096) Wka1 32x64; [4096,8192) Wpa1 32x128
__device__ float  g_fw[8192];

// hardware bf16 converts (v_cvt_pk_bf16_f32)
__device__ __forceinline__ uint pk2(float lo, float hi) {
  __hip_bfloat162 h = __float22bfloat162_rn(make_float2(lo, hi));
  return *(uint*)&h;
}
__device__ __forceinline__ ushort f2bf(float f) {
  __hip_bfloat16 h = __float2bfloat16(f);
  return *(ushort*)&h;
}
__device__ __forceinline__ int4 pack8(float4 a, float4 b) {
  int4 o;
  o.x = pk2(a.x, a.y); o.y = pk2(a.z, a.w);
  o.z = pk2(b.x, b.y); o.w = pk2(b.z, b.w);
  return o;
}
__device__ __forceinline__ f32x4 mfma16(s16x8 a, s16x8 b, f32x4 c) {
  return __builtin_amdgcn_mfma_f32_16x16x32_bf16(a, b, c, 0, 0, 0);
}
// weight B-frag reads, swizzled rows of 256B / 128B
__device__ __forceinline__ s16x8 ldw256(const ushort* W, int row, int g) {
  return *(const s16x8*)((const char*)W + row * 256 + ((g ^ (row & 7)) << 4));
}
__device__ __forceinline__ s16x8 ldw128(const ushort* W, int row, int g) {
  return *(const s16x8*)((const char*)W + row * 128 + ((g ^ (row & 7)) << 4));
}
__device__ __forceinline__ s16x8 ldfrag_g8(const float* p) {
  float4 a = *(const float4*)p, b = *(const float4*)(p + 4);
  union { int4 i; s16x8 s; } u;
  u.i = pack8(a, b);
  return u.s;
}
// store a 16x64 half C tile (tiles t=0..3) into 128B-row swizzled buffer
__device__ __forceinline__ void st16h(char* bufb, int t, f32x4 c, int l, int cq,
                                      bool dorelu) {
  const int colp = (l & 15) + 16 * t;   // 0..63
  const int g = colp >> 3;              // 0..7
  const int off = (colp & 7) * 2;
  #pragma unroll
  for (int rr = 0; rr < 4; ++rr) {
    const int row = cq * 4 + rr;
    float v = dorelu ? fmaxf(c[rr], 0.f) : c[rr];
    *(ushort*)(bufb + row * 128 + ((g ^ (row & 7)) << 4) + off) = f2bf(v);
  }
}
// store a C tile (16 cols at n-tile t) bf16 into 16x128 swizzled buffer (k_post)
__device__ __forceinline__ void st16(char* bufb, int t, f32x4 c, int l, int cq,
                                     bool dorelu) {
  const int colp = (l & 15) + 16 * t;
  const int g = colp >> 3;
  const int off = (colp & 7) * 2;
  #pragma unroll
  for (int rr = 0; rr < 4; ++rr) {
    const int row = cq * 4 + rr;
    float v = dorelu ? fmaxf(c[rr], 0.f) : c[rr];
    *(ushort*)(bufb + row * 256 + ((g ^ (row & 7)) << 4) + off) = f2bf(v);
  }
}
// store 16x32 a1 tile (row stride 64B) with relu, b16 writes
__device__ __forceinline__ void st16_a1(char* bufb, int t, f32x4 c, int l, int cq) {
  const int colp = (l & 15) + 16 * t;   // 0..31
  const int g = colp >> 3;              // 0..3
  const int off = (colp & 7) * 2;
  #pragma unroll
  for (int rr = 0; rr < 4; ++rr) {
    const int row = cq * 4 + rr;
    *(ushort*)(bufb + row * 64 + ((g ^ (row & 3)) << 4) + off) =
        f2bf(fmaxf(c[rr], 0.f));
  }
}

// ---------------- Kernel 0: fused weights  Wa1 @ {Wq, Wk, Wp2} ---------------
__global__ __launch_bounds__(256) void k_fuse(
    const float* __restrict__ Wq, const float* __restrict__ Wk,
    const float* __restrict__ Wp2, const float* __restrict__ Wa1)
{
  const int t = blockIdx.x * 256 + threadIdx.x;   // 0..8191
  if (t < 2048) {
    int m = t >> 6, c = t & 63;
    float s = 0.f;
    for (int o = 0; o < COUT; ++o) s += Wa1[m * COUT + o] * Wq[o * CIN + c];
    g_fw[t] = s;
  } else if (t < 4096) {
    int u = t - 2048;
    int m = u >> 6, c = u & 63;
    float s = 0.f;
    for (int o = 0; o < COUT; ++o) s += Wa1[m * COUT + o] * Wk[o * CIN + c];
    g_fw[t] = s;
  } else {
    int u = t - 4096;
    int m = u >> 7, c = u & 127;
    float s = 0.f;
    for (int o = 0; o < COUT; ++o) s += Wa1[m * COUT + o] * Wp2[o * COUT + c];
    g_fw[t] = s;
  }
}

// --- Kernel 1: attention core (P=1, 12 waves = 768 thr, 1 block/CU) ---------
// Session-best config (R12): 80 VGPR, no spill, ~31% occupancy (3 waves/SIMD,
// the max the ~132 total regs/wave allows), k_attn ~100 us.
__global__ __launch_bounds__(768) void k_attn(
    const float* __restrict__ xyz, const float* __restrict__ feats,
    const int* __restrict__ idx_fps, const int* __restrict__ idx_knn,
    const float* __restrict__ Wv, const float* __restrict__ Wp1,
    const float* __restrict__ Wp2, const float* __restrict__ Wa2,
    float* __restrict__ out_xyz)
{
  __shared__ ushort lWv[COUT * CIN];     // 16 KB, 128B rows swz
  __shared__ ushort lWp1[COUT * 8];      // 2 KB, 16B rows linear
  __shared__ ushort lWp2[COUT * COUT];   // 32 KB, 256B rows swz
  __shared__ ushort lWka1[MID_ * CIN];   // 4 KB, 128B rows swz (holds -Wka1)
  __shared__ ushort lWpa1[MID_ * COUT];  // 8 KB, 256B rows swz
  __shared__ ushort sbuf[12 * 1024];     // per wave 2KB: nfeat -> t1h1 -> t1h2 -> a1

  const int tid = threadIdx.x;
  const int w = tid >> 6, l = tid & 63;   // w = 0..11
  const int r = l & 15, cq = l >> 4;

  for (int i = tid; i < COUT * CIN / 2; i += 768) {
    int row = i >> 5; int kp = (i & 31) * 2;
    int g = kp >> 3;
    *(uint*)((char*)lWv + row * 128 + ((g ^ (row & 7)) << 4) + (kp & 7) * 2)
        = pk2(Wv[row * CIN + kp], Wv[row * CIN + kp + 1]);
  }
  if (tid < 512) { // Wp1 padded: 128 rows x 4 pairs
    int row = tid >> 2; int kp = (tid & 3) * 2;
    float lo = (kp < 3) ? Wp1[row * 3 + kp] : 0.f;
    float hi = (kp + 1 < 3) ? Wp1[row * 3 + kp + 1] : 0.f;
    *(uint*)((char*)lWp1 + row * 16 + kp * 2) = pk2(lo, hi);
  }
  for (int i = tid; i < COUT * CIN; i += 768) {
    int row = i >> 6; int kp = (i & 63) * 2;
    int g = kp >> 3;
    *(uint*)((char*)lWp2 + row * 256 + ((g ^ (row & 7)) << 4) + (kp & 7) * 2)
        = pk2(Wp2[row * COUT + kp], Wp2[row * COUT + kp + 1]);
  }
  for (int i = tid; i < MID_ * CIN / 2; i += 768) {   // -Wka1
    int row = i >> 5; int kp = (i & 31) * 2;
    int g = kp >> 3;
    const float* src = g_fw + 2048 + row * CIN + kp;
    *(uint*)((char*)lWka1 + row * 128 + ((g ^ (row & 7)) << 4) + (kp & 7) * 2)
        = pk2(-src[0], -src[1]);
  }
  for (int i = tid; i < MID_ * COUT / 2; i += 768) {  // Wpa1
    int row = i >> 6; int kp = (i & 63) * 2;
    int g = kp >> 3;
    const float* src = g_fw + 4096 + row * COUT + kp;
    *(uint*)((char*)lWpa1 + row * 256 + ((g ^ (row & 7)) << 4) + (kp & 7) * 2)
        = pk2(src[0], src[1]);
  }

  // register-resident Wa2 B-frags (8 n-tiles, 32 VGPR)
  s16x8 fWa2[8];
  #pragma unroll
  for (int t = 0; t < 8; ++t)
    fWa2[t] = ldfrag_g8(Wa2 + (16 * t + r) * MID_ + cq * 8);

  __syncthreads();

  char* bufb = (char*)(sbuf + w * 1024);        // 2 KB
  // waves 0-7: 11 points; waves 8-11: 10 points  (8*11 + 4*10 = 128/block)
  const int cnt  = (w < 8) ? 11 : 10;
  const int pid0 = blockIdx.x * 128 + ((w < 8) ? w * 11 : 88 + (w - 8) * 10);

  // ---- prologue: stage sfeat (rows 0..cnt-1 = points, rest dup), qa1 GEMM ----
  {
    const int rp = (r < cnt) ? r : 0;
    const int p = pid0 + rp;
    const int bb = p >> 13;
    const int si = idx_fps[p];
    const float* fs = feats + ((size_t)bb * N_ + si) * CIN;
    #pragma unroll
    for (int j = 0; j < 2; ++j) {
      int g = cq * 2 + j;
      int4 pks = pack8(*(const float4*)(fs + g * 8), *(const float4*)(fs + g * 8 + 4));
      *(int4*)(bufb + r * 128 + ((g ^ (r & 7)) << 4)) = pks;
      if (r < cnt) *(int4*)((char*)g_sfeat + (size_t)p * 128 + g * 16) = pks;
    }
    if (l < 3 * cnt) {
      int pi = l / 3, j = l - pi * 3;
      int pp = pid0 + pi;
      out_xyz[(size_t)pp * 3 + j] =
          xyz[((size_t)(pp >> 13) * N_ + idx_fps[pp]) * 3 + j];
    }
  }
  f32x4 qa1[2];
  qa1[0] = (f32x4){0, 0, 0, 0}; qa1[1] = (f32x4){0, 0, 0, 0};
  {
    s16x8 fS[2], fQ;
    #pragma unroll
    for (int ks = 0; ks < 2; ++ks)
      fS[ks] = *(const s16x8*)(bufb + r * 128 + (((ks * 4 + cq) ^ (r & 7)) << 4));
    #pragma unroll
    for (int ks = 0; ks < 2; ++ks)
      #pragma unroll
      for (int t = 0; t < 2; ++t) {
        fQ = ldfrag_g8(g_fw + (16 * t + r) * CIN + ks * 32 + cq * 8);
        qa1[t] = mfma16(fS[ks], fQ, qa1[t]);
      }
  }

  // ---- per-point loop (gather in-loop; 12 waves/CU of TLP hide latency) -----
  #pragma unroll 1
  for (int i = 0; i < cnt; ++i) {
    const int pid = pid0 + i;
    const int bb = pid >> 13;
    const int nid = idx_knn[(size_t)pid * K_ + r];
    const float* fn = feats + ((size_t)bb * N_ + nid) * CIN + cq * 16;
    float4 f0 = ((const float4*)fn)[0], f1 = ((const float4*)fn)[1];
    float4 f2 = ((const float4*)fn)[2], f3 = ((const float4*)fn)[3];

    s16x8 fRel = {0, 0, 0, 0, 0, 0, 0, 0};
    if (cq == 0) {
      const float* xn = xyz + ((size_t)bb * N_ + nid) * 3;
      const float* xs = xyz + ((size_t)bb * N_ + idx_fps[pid]) * 3;
      fRel[0] = (short)f2bf(xn[0] - xs[0]);
      fRel[1] = (short)f2bf(xn[1] - xs[1]);
      fRel[2] = (short)f2bf(xn[2] - xs[2]);
    }

    // stage nfeat (16 x 64 bf16, 128B swizzled rows)
    {
      int g0 = cq * 2;
      *(int4*)(bufb + r * 128 + ((g0 ^ (r & 7)) << 4)) = pack8(f0, f1);
      *(int4*)(bufb + r * 128 + (((g0 + 1) ^ (r & 7)) << 4)) = pack8(f2, f3);
    }

    // A-frags of staged nfeat (read BEFORE t1h1 overwrites the buffer)
    s16x8 fA[2];
    #pragma unroll
    for (int ks = 0; ks < 2; ++ks)
      fA[ks] = *(const s16x8*)(bufb + r * 128 + (((ks * 4 + cq) ^ (r & 7)) << 4));

    // t1 half1 = relu(rel @ Wp1^T), tiles 0..3 -> buf (overwrites nfeat)
    #pragma unroll
    for (int t = 0; t < 4; ++t) {
      f32x4 z = {0, 0, 0, 0};
      f32x4 c = mfma16(fRel, *(const s16x8*)((const char*)lWp1 + (16 * t + r) * 16), z);
      st16h(bufb, t, c, l, cq, true);
    }

    // acc_v = nfeat @ Wv^T ; za1 = -(nfeat @ Wka1^T)  (cover t1h1 store->read)
    f32x4 vv[8];
    #pragma unroll
    for (int t = 0; t < 8; ++t) vv[t] = (f32x4){0, 0, 0, 0};
    #pragma unroll
    for (int ks = 0; ks < 2; ++ks)
      #pragma unroll
      for (int t = 0; t < 8; ++t)
        vv[t] = mfma16(fA[ks], ldw128(lWv, 16 * t + r, ks * 4 + cq), vv[t]);
    f32x4 za[2];
    za[0] = (f32x4){0, 0, 0, 0}; za[1] = (f32x4){0, 0, 0, 0};
    #pragma unroll
    for (int ks = 0; ks < 2; ++ks)
      #pragma unroll
      for (int t = 0; t < 2; ++t)
        za[t] = mfma16(fA[ks], ldw128(lWka1, 16 * t + r, ks * 4 + cq), za[t]);

    // read t1 half1 A-frags (k = 0..63)
    s16x8 fT0[2];
    #pragma unroll
    for (int ks = 0; ks < 2; ++ks)
      fT0[ks] = *(const s16x8*)(bufb + r * 128 + (((ks * 4 + cq) ^ (r & 7)) << 4));

    // t1 half2, tiles 4..7 -> buf (overwrites half1)
    #pragma unroll
    for (int t = 0; t < 4; ++t) {
      f32x4 z = {0, 0, 0, 0};
      f32x4 c = mfma16(fRel,
                       *(const s16x8*)((const char*)lWp1 + (16 * (t + 4) + r) * 16), z);
      st16h(bufb, t, c, l, cq, true);
    }

    // pe/za with half1 (Wp2/Wpa1 k-cols 0..63) — covers t1h2 store->read
    #pragma unroll
    for (int ks = 0; ks < 2; ++ks)
      #pragma unroll
      for (int t = 0; t < 8; ++t)
        vv[t] = mfma16(fT0[ks], ldw256(lWp2, 16 * t + r, ks * 4 + cq), vv[t]);
    #pragma unroll
    for (int ks = 0; ks < 2; ++ks)
      #pragma unroll
      for (int t = 0; t < 2; ++t)
        za[t] = mfma16(fT0[ks], ldw256(lWpa1, 16 * t + r, ks * 4 + cq), za[t]);

    // read t1 half2 A-frags (k = 64..127)
    s16x8 fT1[2];
    #pragma unroll
    for (int ks = 0; ks < 2; ++ks)
      fT1[ks] = *(const s16x8*)(bufb + r * 128 + (((ks * 4 + cq) ^ (r & 7)) << 4));

    // pe/za with half2 (Wp2/Wpa1 k-cols 64..127)
    #pragma unroll
    for (int ks = 0; ks < 2; ++ks)
      #pragma unroll
      for (int t = 0; t < 8; ++t)
        vv[t] = mfma16(fT1[ks], ldw256(lWp2, 16 * t + r, (ks + 2) * 4 + cq), vv[t]);
    #pragma unroll
    for (int ks = 0; ks < 2; ++ks)
      #pragma unroll
      for (int t = 0; t < 2; ++t)
        za[t] = mfma16(fT1[ks], ldw256(lWpa1, 16 * t + r, (ks + 2) * 4 + cq), za[t]);

    // za1 += qa1[point i] broadcast; relu; -> a1 in buf (half2 consumed)
    const int ii = i & 3, iq = i >> 2;
    #pragma unroll
    for (int t = 0; t < 2; ++t) {
      float qsel = ii == 0 ? qa1[t][0] : ii == 1 ? qa1[t][1]
                 : ii == 2 ? qa1[t][2] : qa1[t][3];
      float qv = __shfl(qsel, (iq << 4) + (l & 15));
      f32x4 ta = za[t];
      #pragma unroll
      for (int rr = 0; rr < 4; ++rr) ta[rr] += qv;
      st16_a1(bufb, t, ta, l, cq);
    }
    // w = a1 @ Wa2^T (B from registers) — per-tile fused softmax keeps only
    // one 16x16 logit tile live (acc peak 52 vs 80)
    s16x8 fA1 = *(const s16x8*)(bufb + r * 64 + ((cq ^ (r & 3)) << 4));
    #pragma unroll
    for (int t = 0; t < 8; ++t) {
      f32x4 z = {0, 0, 0, 0};
      f32x4 wwt = mfma16(fA1, fWa2[t], z);
      float m = fmaxf(fmaxf(wwt[0], wwt[1]), fmaxf(wwt[2], wwt[3]));
      m = fmaxf(m, __shfl_xor(m, 16));
      m = fmaxf(m, __shfl_xor(m, 32));
      float e0 = __expf(wwt[0] - m), e1 = __expf(wwt[1] - m);
      float e2 = __expf(wwt[2] - m), e3 = __expf(wwt[3] - m);
      float ss = e0 + e1 + e2 + e3;
      ss += __shfl_xor(ss, 16);
      ss += __shfl_xor(ss, 32);
      float acc = e0 * vv[t][0] + e1 * vv[t][1] + e2 * vv[t][2] + e3 * vv[t][3];
      acc += __shfl_xor(acc, 16);
      acc += __shfl_xor(acc, 32);
      float outv = acc / ss;
      if (cq == (t >> 2)) {
        int colp = (l & 15) + 16 * t;
        *(ushort*)((char*)g_attn + (size_t)pid * 256 + colp * 2) = f2bf(outv);
      }
    }
  }
}

// ---------------- Kernel 2: proj + res + LN + post (M = 16 points) ----------
__global__ __launch_bounds__(512, 2) void k_post(
    const float* __restrict__ Wproj, const float* __restrict__ Wres,
    const float* __restrict__ Wpost, const float* __restrict__ ln_w,
    const float* __restrict__ ln_b, float* __restrict__ out_main)
{
  __shared__ ushort lWpj[COUT * COUT];
  __shared__ ushort lWrs[COUT * CIN];
  __shared__ ushort lWps[COUT * COUT];
  __shared__ float  llnw[COUT], llnb[COUT];
  __shared__ ushort sbuf[8 * 16 * COUT];

  const int tid = threadIdx.x;
  const int w = tid >> 6, l = tid & 63;
  const int r = l & 15, cq = l >> 4;

  for (int i = tid; i < COUT * CIN; i += 512) {
    int row = i >> 6; int kp = (i & 63) * 2;
    int g = kp >> 3;
    *(uint*)((char*)lWpj + row * 256 + ((g ^ (row & 7)) << 4) + (kp & 7) * 2)
        = pk2(Wproj[row * COUT + kp], Wproj[row * COUT + kp + 1]);
  }
  for (int i = tid; i < COUT * CIN / 2; i += 512) {
    int row = i >> 5; int kp = (i & 31) * 2;
    int g = kp >> 3;
    *(uint*)((char*)lWrs + row * 128 + ((g ^ (row & 7)) << 4) + (kp & 7) * 2)
        = pk2(Wres[row * CIN + kp], Wres[row * CIN + kp + 1]);
  }
  for (int i = tid; i < COUT * CIN; i += 512) {
    int row = i >> 6; int kp = (i & 63) * 2;
    int g = kp >> 3;
    *(uint*)((char*)lWps + row * 256 + ((g ^ (row & 7)) << 4) + (kp & 7) * 2)
        = pk2(Wpost[row * COUT + kp], Wpost[row * COUT + kp + 1]);
  }
  if (tid < COUT) { llnw[tid] = ln_w[tid]; llnb[tid] = ln_b[tid]; }
  __syncthreads();

  const int T = blockIdx.x * 8 + w;     // 16-point tile id
  char* bufb = (char*)(sbuf + w * 16 * COUT);

  f32x4 acc[8];
  #pragma unroll
  for (int t = 0; t < 8; ++t) acc[t] = (f32x4){0, 0, 0, 0};

  s16x8 fA[4];
  #pragma unroll
  for (int ks = 0; ks < 4; ++ks)
    fA[ks] = *(const s16x8*)(g_attn + ((size_t)T * 16 + r) * COUT + ks * 32 + cq * 8);
  #pragma unroll
  for (int ks = 0; ks < 4; ++ks)
    #pragma unroll
    for (int t = 0; t < 8; ++t)
      acc[t] = mfma16(fA[ks], ldw256(lWpj, 16 * t + r, ks * 4 + cq), acc[t]);

  s16x8 fS[2];
  #pragma unroll
  for (int ks = 0; ks < 2; ++ks)
    fS[ks] = *(const s16x8*)(g_sfeat + ((size_t)T * 16 + r) * CIN + ks * 32 + cq * 8);
  #pragma unroll
  for (int ks = 0; ks < 2; ++ks)
    #pragma unroll
    for (int t = 0; t < 8; ++t)
      acc[t] = mfma16(fS[ks], ldw128(lWrs, 16 * t + r, ks * 4 + cq), acc[t]);

  // LayerNorm per row (= point)
  #pragma unroll
  for (int rr = 0; rr < 4; ++rr) {
    float s1 = 0.f, s2 = 0.f;
    #pragma unroll
    for (int t = 0; t < 8; ++t) { float v = acc[t][rr]; s1 += v; s2 += v * v; }
    #pragma unroll
    for (int off = 1; off < 16; off <<= 1) {
      s1 += __shfl_xor(s1, off);
      s2 += __shfl_xor(s2, off);
    }
    float mu = s1 * (1.f / COUT);
    float rs = rsqrtf(s2 * (1.f / COUT) - mu * mu + EPS_);
    #pragma unroll
    for (int t = 0; t < 8; ++t) {
      int col = (l & 15) + 16 * t;
      acc[t][rr] = (acc[t][rr] - mu) * rs * llnw[col] + llnb[col];
    }
  }
  #pragma unroll
  for (int t = 0; t < 8; ++t) st16(bufb, t, acc[t], l, cq, false);

  // post conv GEMM
  s16x8 fZ[4];
  #pragma unroll
  for (int ks = 0; ks < 4; ++ks)
    fZ[ks] = *(const s16x8*)(bufb + r * 256 + (((ks * 4 + cq) ^ (r & 7)) << 4));
  f32x4 po[8];
  #pragma unroll
  for (int t = 0; t < 8; ++t) po[t] = (f32x4){0, 0, 0, 0};
  #pragma unroll
  for (int ks = 0; ks < 4; ++ks)
    #pragma unroll
    for (int t = 0; t < 8; ++t)
      po[t] = mfma16(fZ[ks], ldw256(lWps, 16 * t + r, ks * 4 + cq), po[t]);

  // write pre-GN post + per-tile GN partials (group = tile t)
  #pragma unroll
  for (int t = 0; t < 8; ++t) {
    float s1 = po[t][0] + po[t][1] + po[t][2] + po[t][3];
    float s2 = po[t][0] * po[t][0] + po[t][1] * po[t][1]
             + po[t][2] * po[t][2] + po[t][3] * po[t][3];
    #pragma unroll
    for (int off = 1; off < 64; off <<= 1) {
      s1 += __shfl_xor(s1, off);
      s2 += __shfl_xor(s2, off);
    }
    if (l == 0) {
      g_part[((size_t)T * 8 + t) * 2] = s1;
      g_part[((size_t)T * 8 + t) * 2 + 1] = s2;
    }
    #pragma unroll
    for (int rr = 0; rr < 4; ++rr) {
      int row = T * 16 + cq * 4 + rr;
      out_main[(size_t)row * COUT + (l & 15) + 16 * t] = po[t][rr];
    }
  }
}

// ---------------- GroupNorm finish + apply ----------------------------------
__global__ void k_gn_finish(void) {
  int bg = blockIdx.x;          // 0..31  (b*8+g)
  int b = bg >> 3, g = bg & 7;
  int t = threadIdx.x;          // 64
  float s1 = 0.f, s2 = 0.f;
  for (int i = t; i < 512; i += 64) {
    size_t T = (size_t)b * 512 + i;
    s1 += g_part[(T * 8 + g) * 2];
    s2 += g_part[(T * 8 + g) * 2 + 1];
  }
  #pragma unroll
  for (int off = 1; off < 64; off <<= 1) {
    s1 += __shfl_xor(s1, off);
    s2 += __shfl_xor(s2, off);
  }
  if (t == 0) {
    float n = (float)S_ * 16.f;
    float mu = s1 / n;
    float var = s2 / n - mu * mu;
    g_stats[bg * 2] = mu;
    g_stats[bg * 2 + 1] = rsqrtf(var + EPS_);
  }
}

__global__ __launch_bounds__(256) void k_gn_apply(
    float* __restrict__ x, const float* __restrict__ gn_w,
    const float* __restrict__ gn_b)
{
  const int i = blockIdx.x * 256 + threadIdx.x;   // float4 index
  if (i >= B_ * S_ * (COUT / 4)) return;
  const int c = (i & 31) * 4;
  const int g = c >> 4;
  const int b = i >> 18;
  const float m = g_stats[(b * 8 + g) * 2];
  const float rv = g_stats[(b * 8 + g) * 2 + 1];
  float4 v = ((float4*)x)[i];
  v.x = fmaxf((v.x - m) * rv * gn_w[c + 0] + gn_b[c + 0], 0.f);
  v.y = fmaxf((v.y - m) * rv * gn_w[c + 1] + gn_b[c + 1], 0.f);
  v.z = fmaxf((v.z - m) * rv * gn_w[c + 2] + gn_b[c + 2], 0.f);
  v.w = fmaxf((v.w - m) * rv * gn_w[c + 3] + gn_b[c + 3], 0.f);
  ((float4*)x)[i] = v;
}

extern "C" void kernel_launch(void* const* d_in, const int* in_sizes, int n_in,
                              void* d_out, int out_size, void* d_ws, size_t ws_size,
                              hipStream_t stream) {
  const float* xyz     = (const float*)d_in[0];
  const float* feats   = (const float*)d_in[1];
  const int*   idx_fps = (const int*)d_in[2];
  const int*   idx_knn = (const int*)d_in[3];
  const float* Wq    = (const float*)d_in[4];
  const float* Wk    = (const float*)d_in[5];
  const float* Wv    = (const float*)d_in[6];
  const float* Wp1   = (const float*)d_in[7];
  const float* Wp2   = (const float*)d_in[8];
  const float* Wa1   = (const float*)d_in[9];
  const float* Wa2   = (const float*)d_in[10];
  const float* Wproj = (const float*)d_in[11];
  const float* ln_w  = (const float*)d_in[12];
  const float* ln_b  = (const float*)d_in[13];
  const float* Wres  = (const float*)d_in[14];
  const float* Wpost = (const float*)d_in[15];
  const float* gn_w  = (const float*)d_in[16];
  const float* gn_b  = (const float*)d_in[17];

  float* out      = (float*)d_out;
  float* out_xyz  = out;
  float* out_main = out + (size_t)B_ * S_ * 3;

  k_fuse<<<dim3(32), dim3(256), 0, stream>>>(Wq, Wk, Wp2, Wa1);
  k_attn<<<dim3(256), dim3(768), 0, stream>>>(
      xyz, feats, idx_fps, idx_knn, Wv, Wp1, Wp2, Wa2, out_xyz);
  k_post<<<dim3(256), dim3(512), 0, stream>>>(
      Wproj, Wres, Wpost, ln_w, ln_b, out_main);
  k_gn_finish<<<dim3(32), dim3(64), 0, stream>>>();
  k_gn_apply<<<dim3((B_ * S_ * (COUT / 4) + 255) / 256), dim3(256), 0, stream>>>(
      out_main, gn_w, gn_b);
}